// Round 4
// baseline (472.495 us; speedup 1.0000x reference)
//
#include <hip/hip_runtime.h>

#define NP   8192
#define BB   4
#define DIN  32
#define M0   32
#define M1   32
#define M2   64
#define CAP  80
#define KWV  16            // waves per knn block
#define SEG  (NP / KWV)    // 512 points per wave

typedef float v2f __attribute__((ext_vector_type(2)));

__device__ __forceinline__ float lrelu(float x) { return fmaxf(x, 0.1f * x); }
__device__ __forceinline__ unsigned umin_(unsigned a, unsigned b) { return a < b ? a : b; }
__device__ __forceinline__ unsigned umax_(unsigned a, unsigned b) { return a > b ? a : b; }

// monotonic float->uint key (total order incl. negatives)
__device__ __forceinline__ unsigned fkey(float f) {
    unsigned b = __float_as_uint(f);
    return (b & 0x80000000u) ? ~b : (b | 0x80000000u);
}
__device__ __forceinline__ float funkey(unsigned k) {
    unsigned b = (k & 0x80000000u) ? (k & 0x7fffffffu) : ~k;
    return __uint_as_float(b);
}

// round-to-nearest-even f32 -> bf16 (as uint16 in low bits)
__device__ __forceinline__ unsigned bf16rn(float f) {
    unsigned u = __float_as_uint(f);
    unsigned r = (u >> 16) & 1u;
    return (u + 0x7fffu + r) >> 16;
}

// ---------------------------------------------------------------------------
// Kernel 1: pack pts (AoS float4 + SoA X/Y/Z/W) and feat = W0[:,3:] @ points
// stored as bf16 pairs (uint = lo:even elem, hi:odd elem).
// Block = 4 waves over the same 64 points; wave w computes outputs [8w,8w+8).
// ---------------------------------------------------------------------------
__global__ __launch_bounds__(256) void prep_kernel(
    const float* __restrict__ xyz, const float* __restrict__ points,
    const float* __restrict__ W0, float4* __restrict__ pts4,
    float* __restrict__ X, float* __restrict__ Y, float* __restrict__ Z,
    float* __restrict__ Wsq, unsigned* __restrict__ featb)
{
    const int tid  = threadIdx.x;
    const int w    = __builtin_amdgcn_readfirstlane(tid >> 6);  // 0..3
    const int lane = tid & 63;
    const int t    = blockIdx.x * 64 + lane;     // point id, 512 blocks
    const int b    = t >> 13;
    const int n    = t & (NP - 1);

    if (w == 0) {
        const float* xb = xyz + (size_t)b * 3 * NP;
        float x = xb[n], y = xb[NP + n], z = xb[2 * NP + n];
        float s = x * x + y * y + z * z;
        pts4[t] = make_float4(x, y, z, s);
        X[t] = x; Y[t] = y; Z[t] = z; Wsq[t] = s;
    }

    const float* pb = points + (size_t)b * DIN * NP + n;
    float p[DIN];
#pragma unroll
    for (int c = 0; c < DIN; ++c) p[c] = pb[c * NP];

    uint4 outv;
    unsigned* ov = (unsigned*)&outv;
#pragma unroll
    for (int r = 0; r < 4; ++r) {
        int oe = w * 8 + 2 * r;
        float a0 = 0.f, a1 = 0.f;
#pragma unroll
        for (int c = 0; c < DIN; ++c) {
            a0 = fmaf(W0[oe * 35 + 3 + c], p[c], a0);
            a1 = fmaf(W0[(oe + 1) * 35 + 3 + c], p[c], a1);
        }
        ov[r] = bf16rn(a0) | (bf16rn(a1) << 16);
    }
    *(uint4*)(featb + (size_t)t * 16 + w * 4) = outv;
}

// ---------------------------------------------------------------------------
// Kernel 2: exact 16-NN. 16 waves/block, 64 queries (lane = query).
// Metric t = |p|^2 - 2 q.p (order-preserving shift of d per query).
// SoA point arrays -> wave-uniform scan index -> batched s_loads.
// Packed float2 pairs -> v_pk_fma_f32: 5 VOP3P per 2 points.
// Pass 1: per-wave 32 class minima (class = j mod 32) -> ds_min merge.
// T = 16th smallest of 32 global class minima (>=16 distinct pts <= T).
// Pass 2: append t<=T candidates (identical packed arithmetic -> same bits);
// exact (t,idx)-lex top-16 per query; overflow -> exact full scan.
// ---------------------------------------------------------------------------
__global__ __launch_bounds__(1024, 8) void knn_kernel(
    const float4* __restrict__ pts4,
    const float* __restrict__ X, const float* __restrict__ Y,
    const float* __restrict__ Z, const float* __restrict__ Wsq,
    int* __restrict__ idxout)
{
    __shared__ unsigned skey[32 * 64];     // 8 KB global class-min keys
    __shared__ float cand_t[CAP * 64];     // 20 KB
    __shared__ int   cand_i[CAP * 64];     // 20 KB
    __shared__ float sT[64];
    __shared__ int   scnt[64];

    const int tid  = threadIdx.x;
    const int w    = __builtin_amdgcn_readfirstlane(tid >> 6);
    const int lane = tid & 63;
    const int blk  = blockIdx.x;           // 512 blocks
    const int b    = blk >> 7;
    const int n0   = (blk & 127) << 6;
    const int bn0  = b * NP;
    const float4 me = pts4[bn0 + n0 + lane];
    const float* Xb = X + bn0; const float* Yb = Y + bn0;
    const float* Zb = Z + bn0; const float* Wb = Wsq + bn0;
    const v2f qx2 = {me.x, me.x}, qy2 = {me.y, me.y}, qz2 = {me.z, me.z};
    const v2f n2 = {-2.f, -2.f};

    skey[tid] = 0xFFFFFFFFu;
    skey[tid + 1024] = 0xFFFFFFFFu;
    if (tid < 64) scnt[tid] = 0;
    __syncthreads();

    // ---- pass 1: per-wave class minima over packed pairs ----
    v2f m2[16];
#pragma unroll
    for (int c = 0; c < 16; ++c) m2[c] = (v2f){1e30f, 1e30f};
    const int base = w * SEG;
    for (int i = 0; i < SEG; i += 16) {
#pragma unroll
        for (int c = 0; c < 8; ++c) {
            int j = base + i + 2 * c;
            v2f px = {Xb[j], Xb[j + 1]};
            v2f py = {Yb[j], Yb[j + 1]};
            v2f pz = {Zb[j], Zb[j + 1]};
            v2f pw = {Wb[j], Wb[j + 1]};
            v2f dot = __builtin_elementwise_fma(qx2, px,
                       __builtin_elementwise_fma(qy2, py, qz2 * pz));
            v2f t = __builtin_elementwise_fma(n2, dot, pw);
            int mi = ((i >> 4) & 1) * 8 + c;
            m2[mi] = __builtin_elementwise_min(m2[mi], t);
        }
    }
#pragma unroll
    for (int c = 0; c < 16; ++c) {
        atomicMin(&skey[(2 * c) * 64 + lane], fkey(m2[c].x));
        atomicMin(&skey[(2 * c + 1) * 64 + lane], fkey(m2[c].y));
    }
    __syncthreads();

    // ---- threshold: 16th smallest of the 32 global class minima ----
    if (tid < 64) {
        unsigned t16[16];
#pragma unroll
        for (int i = 0; i < 16; ++i) t16[i] = 0xFFFFFFFFu;
#pragma unroll
        for (int c = 0; c < 32; ++c) {
            unsigned d = skey[c * 64 + tid];
            if (d < t16[15]) {
                t16[15] = d;
#pragma unroll
                for (int i = 15; i > 0; --i) {
                    unsigned a = t16[i - 1], cc = t16[i];
                    t16[i - 1] = umin_(a, cc);
                    t16[i]     = umax_(a, cc);
                }
            }
        }
        sT[tid] = funkey(t16[15]);
    }
    __syncthreads();

    // ---- pass 2: gather candidates with t <= T (identical arithmetic) ----
    const float T = sT[lane];
    for (int i = 0; i < SEG; i += 16) {
#pragma unroll
        for (int c = 0; c < 8; ++c) {
            int j = base + i + 2 * c;
            v2f px = {Xb[j], Xb[j + 1]};
            v2f py = {Yb[j], Yb[j + 1]};
            v2f pz = {Zb[j], Zb[j + 1]};
            v2f pw = {Wb[j], Wb[j + 1]};
            v2f dot = __builtin_elementwise_fma(qx2, px,
                       __builtin_elementwise_fma(qy2, py, qz2 * pz));
            v2f t = __builtin_elementwise_fma(n2, dot, pw);
            if (t.x <= T) {
                int pos = atomicAdd(&scnt[lane], 1);
                if (pos < CAP) { cand_t[pos * 64 + lane] = t.x; cand_i[pos * 64 + lane] = j; }
            }
            if (t.y <= T) {
                int pos = atomicAdd(&scnt[lane], 1);
                if (pos < CAP) { cand_t[pos * 64 + lane] = t.y; cand_i[pos * 64 + lane] = j + 1; }
            }
        }
    }
    __syncthreads();

    // ---- exact selection among candidates (lane = query) ----
    if (tid < 64) {
        int cnt = scnt[tid];
        int* outp = idxout + ((bn0 + n0 + tid) << 4);
        float bd[16]; int bi[16];
#pragma unroll
        for (int i = 0; i < 16; ++i) { bd[i] = 3e38f; bi[i] = 0; }
        if (cnt <= CAP) {
            for (int pos = 0; pos < cnt; ++pos) {
                float d = cand_t[pos * 64 + tid];
                int   j = cand_i[pos * 64 + tid];
                if ((d < bd[15]) || (d == bd[15] && j < bi[15])) {
                    bd[15] = d; bi[15] = j;
#pragma unroll
                    for (int i = 15; i > 0; --i) {
                        bool sw = (bd[i] < bd[i - 1]) || (bd[i] == bd[i - 1] && bi[i] < bi[i - 1]);
                        float td = bd[i - 1]; int tj = bi[i - 1];
                        bd[i - 1] = sw ? bd[i] : td;  bi[i - 1] = sw ? bi[i] : tj;
                        bd[i]     = sw ? td : bd[i];  bi[i]     = sw ? tj : bi[i];
                    }
                }
            }
        } else {
            // overflow fallback (exact, never expected)
            float4 meq = pts4[bn0 + n0 + tid];
            for (int j = 0; j < NP; ++j) {
                float dot = fmaf(meq.x, Xb[j], fmaf(meq.y, Yb[j], meq.z * Zb[j]));
                float d = fmaf(-2.0f, dot, Wb[j]);
                if ((d < bd[15]) || (d == bd[15] && j < bi[15])) {
                    bd[15] = d; bi[15] = j;
#pragma unroll
                    for (int i = 15; i > 0; --i) {
                        bool sw = (bd[i] < bd[i - 1]) || (bd[i] == bd[i - 1] && bi[i] < bi[i - 1]);
                        float td = bd[i - 1]; int tj = bi[i - 1];
                        bd[i - 1] = sw ? bd[i] : td;  bi[i - 1] = sw ? bi[i] : tj;
                        bd[i]     = sw ? td : bd[i];  bi[i]     = sw ? tj : bi[i];
                    }
                }
            }
        }
#pragma unroll
        for (int i = 0; i < 16; ++i) outp[i] = bi[i];
    }
}

// ---------------------------------------------------------------------------
// Kernel 3: gather + conv0/1/2 + max over K. One thread per (n,k) column,
// 512-thread blocks (32 n x 16 k) for memory-level parallelism. feat gathered
// as bf16 (4x dwordx4 per neighbor). k-max via shfl_xor width 16.
// ---------------------------------------------------------------------------
__global__ __launch_bounds__(512, 4) void conv_kernel(
    const float4* __restrict__ pts4, const unsigned* __restrict__ featb,
    const int* __restrict__ idx,
    const float* __restrict__ W0, const float* __restrict__ W1, const float* __restrict__ W2,
    float* __restrict__ out)
{
    __shared__ float so[M2][33];
    const int tid = threadIdx.x;
    const int k   = tid & 15;
    const int nl  = tid >> 4;              // 0..31
    const int blk = blockIdx.x;            // 1024 blocks
    const int b   = blk >> 8;              // 256 blocks per batch
    const int n0  = (blk & 255) << 5;
    const int n   = n0 + nl;
    const int bn  = b * NP + n;
    const int j   = idx[(bn << 4) + k];
    const int bj  = b * NP + j;

    const float4 pc = pts4[bn];
    const float4 pj = pts4[bj];
    const float rx = pj.x - pc.x, ry = pj.y - pc.y, rz = pj.z - pc.z;

    const uint4* fj = (const uint4*)(featb + (size_t)bj * 16);

    float x0[M0];
#pragma unroll
    for (int g = 0; g < 4; ++g) {
        uint4 u = fj[g];
        const unsigned* uv = (const unsigned*)&u;
#pragma unroll
        for (int r = 0; r < 4; ++r) {
            int o = g * 8 + 2 * r;
            float fe = __uint_as_float(uv[r] << 16);
            float fo_ = __uint_as_float(uv[r] & 0xffff0000u);
            x0[o]     = lrelu(fmaf(W0[o * 35], rx, fmaf(W0[o * 35 + 1], ry, fmaf(W0[o * 35 + 2], rz, fe))));
            x0[o + 1] = lrelu(fmaf(W0[(o + 1) * 35], rx, fmaf(W0[(o + 1) * 35 + 1], ry, fmaf(W0[(o + 1) * 35 + 2], rz, fo_))));
        }
    }

    float x1[M1];
#pragma unroll
    for (int o = 0; o < M1; ++o) {
        float acc = 0.f;
#pragma unroll
        for (int c = 0; c < M0; ++c) acc = fmaf(W1[o * 32 + c], x0[c], acc);
        x1[o] = lrelu(acc);
    }

#pragma unroll
    for (int o = 0; o < M2; ++o) {
        float acc = 0.f;
#pragma unroll
        for (int c = 0; c < M1; ++c) acc = fmaf(W2[o * 32 + c], x1[c], acc);
        float v = lrelu(acc);
        v = fmaxf(v, __shfl_xor(v, 1, 16));
        v = fmaxf(v, __shfl_xor(v, 2, 16));
        v = fmaxf(v, __shfl_xor(v, 4, 16));
        v = fmaxf(v, __shfl_xor(v, 8, 16));
        if (k == (o & 15)) so[o][nl] = v;
    }
    __syncthreads();
    {
        int o = tid >> 3;                 // 0..63
        int col = (tid & 7) << 2;         // 0..28
        float4 v = make_float4(so[o][col], so[o][col + 1], so[o][col + 2], so[o][col + 3]);
        *(float4*)(out + ((size_t)(b * M2 + o)) * NP + n0 + col) = v;
    }
}

// ---------------------------------------------------------------------------
extern "C" void kernel_launch(void* const* d_in, const int* in_sizes, int n_in,
                              void* d_out, int out_size, void* d_ws, size_t ws_size,
                              hipStream_t stream)
{
    const float* xyz    = (const float*)d_in[0];
    const float* points = (const float*)d_in[1];
    const float* W0     = (const float*)d_in[2];
    const float* W1     = (const float*)d_in[3];
    const float* W2     = (const float*)d_in[4];
    float* out = (float*)d_out;

    char* ws = (char*)d_ws;
    float4*   pts4  = (float4*)ws;                       // 512 KB
    float*    X     = (float*)(ws + 0x080000);           // 128 KB
    float*    Y     = (float*)(ws + 0x0A0000);           // 128 KB
    float*    Z     = (float*)(ws + 0x0C0000);           // 128 KB
    float*    Wsq   = (float*)(ws + 0x0E0000);           // 128 KB
    unsigned* featb = (unsigned*)(ws + 0x100000);        // 2 MB
    int*      idx   = (int*)(ws + 0x300000);             // 2 MB

    prep_kernel<<<BB * NP / 64, 256,  0, stream>>>(xyz, points, W0, pts4, X, Y, Z, Wsq, featb);
    knn_kernel <<<BB * NP / 64, 1024, 0, stream>>>(pts4, X, Y, Z, Wsq, idx);
    conv_kernel<<<BB * NP / 32, 512,  0, stream>>>(pts4, featb, idx, W0, W1, W2, out);
}

// Round 5
// 281.627 us; speedup vs baseline: 1.6777x; 1.6777x over previous
//
#include <hip/hip_runtime.h>

#define NP   8192
#define BB   4
#define DIN  32
#define M0   32
#define M1   32
#define M2   64
#define CAP  80
#define KWV  16            // waves per knn block
#define SEG  (NP / KWV)    // 512 points per wave

typedef float v2f __attribute__((ext_vector_type(2)));

__device__ __forceinline__ float lrelu(float x) { return fmaxf(x, 0.1f * x); }
__device__ __forceinline__ unsigned umin_(unsigned a, unsigned b) { return a < b ? a : b; }
__device__ __forceinline__ unsigned umax_(unsigned a, unsigned b) { return a > b ? a : b; }

// monotonic float->uint key (total order incl. negatives)
__device__ __forceinline__ unsigned fkey(float f) {
    unsigned b = __float_as_uint(f);
    return (b & 0x80000000u) ? ~b : (b | 0x80000000u);
}
__device__ __forceinline__ float funkey(unsigned k) {
    unsigned b = (k & 0x80000000u) ? (k & 0x7fffffffu) : ~k;
    return __uint_as_float(b);
}

// round-to-nearest-even f32 -> bf16 (as uint16 in low bits)
__device__ __forceinline__ unsigned bf16rn(float f) {
    unsigned u = __float_as_uint(f);
    unsigned r = (u >> 16) & 1u;
    return (u + 0x7fffu + r) >> 16;
}

// ---------------------------------------------------------------------------
// Kernel 1: pack pts (AoS float4 + SoA X/Y/Z/W) and feat = W0[:,3:] @ points
// stored as bf16 pairs (uint = lo:even elem, hi:odd elem).
// Block = 4 waves over the same 64 points; wave w computes outputs [8w,8w+8).
// ---------------------------------------------------------------------------
__global__ __launch_bounds__(256) void prep_kernel(
    const float* __restrict__ xyz, const float* __restrict__ points,
    const float* __restrict__ W0, float4* __restrict__ pts4,
    float* __restrict__ X, float* __restrict__ Y, float* __restrict__ Z,
    float* __restrict__ Wsq, unsigned* __restrict__ featb)
{
    const int tid  = threadIdx.x;
    const int w    = __builtin_amdgcn_readfirstlane(tid >> 6);  // 0..3
    const int lane = tid & 63;
    const int t    = blockIdx.x * 64 + lane;     // point id, 512 blocks
    const int b    = t >> 13;
    const int n    = t & (NP - 1);

    if (w == 0) {
        const float* xb = xyz + (size_t)b * 3 * NP;
        float x = xb[n], y = xb[NP + n], z = xb[2 * NP + n];
        float s = x * x + y * y + z * z;
        pts4[t] = make_float4(x, y, z, s);
        X[t] = x; Y[t] = y; Z[t] = z; Wsq[t] = s;
    }

    const float* pb = points + (size_t)b * DIN * NP + n;
    float p[DIN];
#pragma unroll
    for (int c = 0; c < DIN; ++c) p[c] = pb[c * NP];

    uint4 outv;
    unsigned* ov = (unsigned*)&outv;
#pragma unroll
    for (int r = 0; r < 4; ++r) {
        int oe = w * 8 + 2 * r;
        float a0 = 0.f, a1 = 0.f;
#pragma unroll
        for (int c = 0; c < DIN; ++c) {
            a0 = fmaf(W0[oe * 35 + 3 + c], p[c], a0);
            a1 = fmaf(W0[(oe + 1) * 35 + 3 + c], p[c], a1);
        }
        ov[r] = bf16rn(a0) | (bf16rn(a1) << 16);
    }
    *(uint4*)(featb + (size_t)t * 16 + w * 4) = outv;
}

// ---------------------------------------------------------------------------
// Kernel 2: exact 16-NN. 16 waves/block, 64 queries (lane = query).
// Metric t = |p|^2 - 2 q.p (order-preserving shift of d per query).
// SoA point arrays -> wave-uniform scan index -> batched s_loads.
// Packed float2 pairs -> v_pk_fma_f32: 5 VOP3P per 2 points.
// Pass 1: per-wave 32 class minima, class = j mod 32, STATIC register index
//         (m2[c] pair covers classes 2c, 2c+1) -> ds_min merge in key space.
// T = 16th smallest of 32 global class minima (>=16 distinct pts <= T).
// Pass 2: append t<=T candidates (bit-identical packed arithmetic);
// exact (t,idx)-lex top-16 per query; overflow -> exact full scan.
// ---------------------------------------------------------------------------
__global__ __launch_bounds__(1024, 8) void knn_kernel(
    const float4* __restrict__ pts4,
    const float* __restrict__ X, const float* __restrict__ Y,
    const float* __restrict__ Z, const float* __restrict__ Wsq,
    int* __restrict__ idxout)
{
    __shared__ unsigned skey[32 * 64];     // 8 KB global class-min keys
    __shared__ float cand_t[CAP * 64];     // 20 KB
    __shared__ int   cand_i[CAP * 64];     // 20 KB
    __shared__ float sT[64];
    __shared__ int   scnt[64];

    const int tid  = threadIdx.x;
    const int w    = __builtin_amdgcn_readfirstlane(tid >> 6);
    const int lane = tid & 63;
    const int blk  = blockIdx.x;           // 512 blocks
    const int b    = blk >> 7;
    const int n0   = (blk & 127) << 6;
    const int bn0  = b * NP;
    const float4 me = pts4[bn0 + n0 + lane];
    const float* Xb = X + bn0; const float* Yb = Y + bn0;
    const float* Zb = Z + bn0; const float* Wb = Wsq + bn0;
    const v2f qx2 = {me.x, me.x}, qy2 = {me.y, me.y}, qz2 = {me.z, me.z};
    const v2f n2 = {-2.f, -2.f};

    skey[tid] = 0xFFFFFFFFu;
    skey[tid + 1024] = 0xFFFFFFFFu;
    if (tid < 64) scnt[tid] = 0;
    __syncthreads();

    // ---- pass 1: per-wave class minima, 32 points (16 pairs) per iter ----
    v2f m2[16];
#pragma unroll
    for (int c = 0; c < 16; ++c) m2[c] = (v2f){1e30f, 1e30f};
    const int base = w * SEG;
    for (int i = 0; i < SEG; i += 32) {
#pragma unroll
        for (int c = 0; c < 16; ++c) {           // j mod 32 == {2c, 2c+1}
            int j = base + i + 2 * c;
            v2f px = {Xb[j], Xb[j + 1]};
            v2f py = {Yb[j], Yb[j + 1]};
            v2f pz = {Zb[j], Zb[j + 1]};
            v2f pw = {Wb[j], Wb[j + 1]};
            v2f dot = __builtin_elementwise_fma(qx2, px,
                       __builtin_elementwise_fma(qy2, py, qz2 * pz));
            v2f t = __builtin_elementwise_fma(n2, dot, pw);
            m2[c] = __builtin_elementwise_min(m2[c], t);
        }
    }
#pragma unroll
    for (int c = 0; c < 16; ++c) {
        atomicMin(&skey[(2 * c) * 64 + lane], fkey(m2[c].x));
        atomicMin(&skey[(2 * c + 1) * 64 + lane], fkey(m2[c].y));
    }
    __syncthreads();

    // ---- threshold: 16th smallest of the 32 global class minima ----
    if (tid < 64) {
        unsigned t16[16];
#pragma unroll
        for (int i = 0; i < 16; ++i) t16[i] = 0xFFFFFFFFu;
#pragma unroll
        for (int c = 0; c < 32; ++c) {
            unsigned d = skey[c * 64 + tid];
            if (d < t16[15]) {
                t16[15] = d;
#pragma unroll
                for (int i = 15; i > 0; --i) {
                    unsigned a = t16[i - 1], cc = t16[i];
                    t16[i - 1] = umin_(a, cc);
                    t16[i]     = umax_(a, cc);
                }
            }
        }
        sT[tid] = funkey(t16[15]);
    }
    __syncthreads();

    // ---- pass 2: gather candidates with t <= T (identical arithmetic) ----
    const float T = sT[lane];
    for (int i = 0; i < SEG; i += 16) {
#pragma unroll
        for (int c = 0; c < 8; ++c) {
            int j = base + i + 2 * c;
            v2f px = {Xb[j], Xb[j + 1]};
            v2f py = {Yb[j], Yb[j + 1]};
            v2f pz = {Zb[j], Zb[j + 1]};
            v2f pw = {Wb[j], Wb[j + 1]};
            v2f dot = __builtin_elementwise_fma(qx2, px,
                       __builtin_elementwise_fma(qy2, py, qz2 * pz));
            v2f t = __builtin_elementwise_fma(n2, dot, pw);
            if (t.x <= T) {
                int pos = atomicAdd(&scnt[lane], 1);
                if (pos < CAP) { cand_t[pos * 64 + lane] = t.x; cand_i[pos * 64 + lane] = j; }
            }
            if (t.y <= T) {
                int pos = atomicAdd(&scnt[lane], 1);
                if (pos < CAP) { cand_t[pos * 64 + lane] = t.y; cand_i[pos * 64 + lane] = j + 1; }
            }
        }
    }
    __syncthreads();

    // ---- exact selection among candidates (lane = query) ----
    if (tid < 64) {
        int cnt = scnt[tid];
        int* outp = idxout + ((bn0 + n0 + tid) << 4);
        float bd[16]; int bi[16];
#pragma unroll
        for (int i = 0; i < 16; ++i) { bd[i] = 3e38f; bi[i] = 0; }
        if (cnt <= CAP) {
            for (int pos = 0; pos < cnt; ++pos) {
                float d = cand_t[pos * 64 + tid];
                int   j = cand_i[pos * 64 + tid];
                if ((d < bd[15]) || (d == bd[15] && j < bi[15])) {
                    bd[15] = d; bi[15] = j;
#pragma unroll
                    for (int i = 15; i > 0; --i) {
                        bool sw = (bd[i] < bd[i - 1]) || (bd[i] == bd[i - 1] && bi[i] < bi[i - 1]);
                        float td = bd[i - 1]; int tj = bi[i - 1];
                        bd[i - 1] = sw ? bd[i] : td;  bi[i - 1] = sw ? bi[i] : tj;
                        bd[i]     = sw ? td : bd[i];  bi[i]     = sw ? tj : bi[i];
                    }
                }
            }
        } else {
            // overflow fallback (exact, never expected)
            float4 meq = pts4[bn0 + n0 + tid];
            for (int j = 0; j < NP; ++j) {
                float dot = fmaf(meq.x, Xb[j], fmaf(meq.y, Yb[j], meq.z * Zb[j]));
                float d = fmaf(-2.0f, dot, Wb[j]);
                if ((d < bd[15]) || (d == bd[15] && j < bi[15])) {
                    bd[15] = d; bi[15] = j;
#pragma unroll
                    for (int i = 15; i > 0; --i) {
                        bool sw = (bd[i] < bd[i - 1]) || (bd[i] == bd[i - 1] && bi[i] < bi[i - 1]);
                        float td = bd[i - 1]; int tj = bi[i - 1];
                        bd[i - 1] = sw ? bd[i] : td;  bi[i - 1] = sw ? bi[i] : tj;
                        bd[i]     = sw ? td : bd[i];  bi[i]     = sw ? tj : bi[i];
                    }
                }
            }
        }
#pragma unroll
        for (int i = 0; i < 16; ++i) outp[i] = bi[i];
    }
}

// ---------------------------------------------------------------------------
// Kernel 3: gather + conv0/1/2 + max over K. One thread per (n,k) column,
// 512-thread blocks (32 n x 16 k) for memory-level parallelism. feat gathered
// as bf16 (4x dwordx4 per neighbor). k-max via shfl_xor width 16.
// ---------------------------------------------------------------------------
__global__ __launch_bounds__(512, 4) void conv_kernel(
    const float4* __restrict__ pts4, const unsigned* __restrict__ featb,
    const int* __restrict__ idx,
    const float* __restrict__ W0, const float* __restrict__ W1, const float* __restrict__ W2,
    float* __restrict__ out)
{
    __shared__ float so[M2][33];
    const int tid = threadIdx.x;
    const int k   = tid & 15;
    const int nl  = tid >> 4;              // 0..31
    const int blk = blockIdx.x;            // 1024 blocks
    const int b   = blk >> 8;              // 256 blocks per batch
    const int n0  = (blk & 255) << 5;
    const int n   = n0 + nl;
    const int bn  = b * NP + n;
    const int j   = idx[(bn << 4) + k];
    const int bj  = b * NP + j;

    const float4 pc = pts4[bn];
    const float4 pj = pts4[bj];
    const float rx = pj.x - pc.x, ry = pj.y - pc.y, rz = pj.z - pc.z;

    const uint4* fj = (const uint4*)(featb + (size_t)bj * 16);

    float x0[M0];
#pragma unroll
    for (int g = 0; g < 4; ++g) {
        uint4 u = fj[g];
        const unsigned* uv = (const unsigned*)&u;
#pragma unroll
        for (int r = 0; r < 4; ++r) {
            int o = g * 8 + 2 * r;
            float fe = __uint_as_float(uv[r] << 16);
            float fo_ = __uint_as_float(uv[r] & 0xffff0000u);
            x0[o]     = lrelu(fmaf(W0[o * 35], rx, fmaf(W0[o * 35 + 1], ry, fmaf(W0[o * 35 + 2], rz, fe))));
            x0[o + 1] = lrelu(fmaf(W0[(o + 1) * 35], rx, fmaf(W0[(o + 1) * 35 + 1], ry, fmaf(W0[(o + 1) * 35 + 2], rz, fo_))));
        }
    }

    float x1[M1];
#pragma unroll
    for (int o = 0; o < M1; ++o) {
        float acc = 0.f;
#pragma unroll
        for (int c = 0; c < M0; ++c) acc = fmaf(W1[o * 32 + c], x0[c], acc);
        x1[o] = lrelu(acc);
    }

#pragma unroll
    for (int o = 0; o < M2; ++o) {
        float acc = 0.f;
#pragma unroll
        for (int c = 0; c < M1; ++c) acc = fmaf(W2[o * 32 + c], x1[c], acc);
        float v = lrelu(acc);
        v = fmaxf(v, __shfl_xor(v, 1, 16));
        v = fmaxf(v, __shfl_xor(v, 2, 16));
        v = fmaxf(v, __shfl_xor(v, 4, 16));
        v = fmaxf(v, __shfl_xor(v, 8, 16));
        if (k == (o & 15)) so[o][nl] = v;
    }
    __syncthreads();
    {
        int o = tid >> 3;                 // 0..63
        int col = (tid & 7) << 2;         // 0..28
        float4 v = make_float4(so[o][col], so[o][col + 1], so[o][col + 2], so[o][col + 3]);
        *(float4*)(out + ((size_t)(b * M2 + o)) * NP + n0 + col) = v;
    }
}

// ---------------------------------------------------------------------------
extern "C" void kernel_launch(void* const* d_in, const int* in_sizes, int n_in,
                              void* d_out, int out_size, void* d_ws, size_t ws_size,
                              hipStream_t stream)
{
    const float* xyz    = (const float*)d_in[0];
    const float* points = (const float*)d_in[1];
    const float* W0     = (const float*)d_in[2];
    const float* W1     = (const float*)d_in[3];
    const float* W2     = (const float*)d_in[4];
    float* out = (float*)d_out;

    char* ws = (char*)d_ws;
    float4*   pts4  = (float4*)ws;                       // 512 KB
    float*    X     = (float*)(ws + 0x080000);           // 128 KB
    float*    Y     = (float*)(ws + 0x0A0000);           // 128 KB
    float*    Z     = (float*)(ws + 0x0C0000);           // 128 KB
    float*    Wsq   = (float*)(ws + 0x0E0000);           // 128 KB
    unsigned* featb = (unsigned*)(ws + 0x100000);        // 2 MB
    int*      idx   = (int*)(ws + 0x300000);             // 2 MB

    prep_kernel<<<BB * NP / 64, 256,  0, stream>>>(xyz, points, W0, pts4, X, Y, Z, Wsq, featb);
    knn_kernel <<<BB * NP / 64, 1024, 0, stream>>>(pts4, X, Y, Z, Wsq, idx);
    conv_kernel<<<BB * NP / 32, 512,  0, stream>>>(pts4, featb, idx, W0, W1, W2, out);
}

// Round 6
// 278.735 us; speedup vs baseline: 1.6951x; 1.0104x over previous
//
#include <hip/hip_runtime.h>

#define NP   8192
#define BB   4
#define DIN  32
#define M0   32
#define M1   32
#define M2   64
#define CAP  80
#define KWV  16            // waves per knn block
#define SEG  (NP / KWV)    // 512 points per wave
#define PPL  (SEG / 64)    // 8 points per lane

__device__ __forceinline__ float lrelu(float x) { return fmaxf(x, 0.1f * x); }
__device__ __forceinline__ unsigned umin_(unsigned a, unsigned b) { return a < b ? a : b; }
__device__ __forceinline__ unsigned umax_(unsigned a, unsigned b) { return a > b ? a : b; }

// monotonic float->uint key (total order incl. negatives)
__device__ __forceinline__ unsigned fkey(float f) {
    unsigned b = __float_as_uint(f);
    return (b & 0x80000000u) ? ~b : (b | 0x80000000u);
}
__device__ __forceinline__ float funkey(unsigned k) {
    unsigned b = (k & 0x80000000u) ? (k & 0x7fffffffu) : ~k;
    return __uint_as_float(b);
}

// round-to-nearest-even f32 -> bf16 (as uint16 in low bits)
__device__ __forceinline__ unsigned bf16rn(float f) {
    unsigned u = __float_as_uint(f);
    unsigned r = (u >> 16) & 1u;
    return (u + 0x7fffu + r) >> 16;
}

// ---------------------------------------------------------------------------
// Kernel 1: pack pts (AoS float4) and feat = W0[:,3:] @ points stored as bf16
// pairs. Block = 4 waves over the same 64 points; wave w computes outs [8w,8w+8).
// ---------------------------------------------------------------------------
__global__ __launch_bounds__(256) void prep_kernel(
    const float* __restrict__ xyz, const float* __restrict__ points,
    const float* __restrict__ W0, float4* __restrict__ pts4,
    unsigned* __restrict__ featb)
{
    const int tid  = threadIdx.x;
    const int w    = __builtin_amdgcn_readfirstlane(tid >> 6);  // 0..3
    const int lane = tid & 63;
    const int t    = blockIdx.x * 64 + lane;     // point id, 512 blocks
    const int b    = t >> 13;
    const int n    = t & (NP - 1);

    if (w == 0) {
        const float* xb = xyz + (size_t)b * 3 * NP;
        float x = xb[n], y = xb[NP + n], z = xb[2 * NP + n];
        float s = x * x + y * y + z * z;
        pts4[t] = make_float4(x, y, z, s);
    }

    const float* pb = points + (size_t)b * DIN * NP + n;
    float p[DIN];
#pragma unroll
    for (int c = 0; c < DIN; ++c) p[c] = pb[c * NP];

    uint4 outv;
    unsigned* ov = (unsigned*)&outv;
#pragma unroll
    for (int r = 0; r < 4; ++r) {
        int oe = w * 8 + 2 * r;
        float a0 = 0.f, a1 = 0.f;
#pragma unroll
        for (int c = 0; c < DIN; ++c) {
            a0 = fmaf(W0[oe * 35 + 3 + c], p[c], a0);
            a1 = fmaf(W0[(oe + 1) * 35 + 3 + c], p[c], a1);
        }
        ov[r] = bf16rn(a0) | (bf16rn(a1) << 16);
    }
    *(uint4*)(featb + (size_t)t * 16 + w * 4) = outv;
}

// ---------------------------------------------------------------------------
// Kernel 2: exact 16-NN, lane = POINT design. 16 waves/block, 64 queries.
// Each lane owns 8 points in registers (coalesced vector loads, no scalar-pipe
// streaming, no pass-2 reload). Metric t = |p|^2 - 2 q.p via precomputed
// (-2qx,-2qy,-2qz) in LDS (static-offset ds_read per q).
// Pass 1: m[q] = min over lane's 8 points (static reg indexing) -> atomicMin
//         merge into skey[q][lane-class] (64 classes per query).
// T[q] = 16th smallest of the 64 class minima (>=16 distinct points <= T).
// Pass 2: m[q]<=T precheck, then bit-identical recompute from registers;
// append to LDS candidates; exact (t,idx)-lex top-16; overflow -> full scan.
// ---------------------------------------------------------------------------
__global__ __launch_bounds__(1024, 4) void knn_kernel(const float4* __restrict__ pts4,
                                                      int* __restrict__ idxout)
{
    __shared__ float4   qc[64];            // (-2x,-2y,-2z,0) per query: 1 KB
    __shared__ unsigned skey[64 * 65];     // padded rows: 16.6 KB
    __shared__ float    sT[64];
    __shared__ int      scnt[64];
    __shared__ float    cand_t[CAP * 64];  // 20 KB
    __shared__ int      cand_i[CAP * 64];  // 20 KB

    const int tid  = threadIdx.x;
    const int w    = __builtin_amdgcn_readfirstlane(tid >> 6);
    const int lane = tid & 63;
    const int blk  = blockIdx.x;           // 512 blocks
    const int b    = blk >> 7;
    const int n0   = (blk & 127) << 6;
    const int bn0  = b * NP;
    const float4* P = pts4 + bn0;

    for (int i = tid; i < 64 * 65; i += 1024) skey[i] = 0xFFFFFFFFu;
    if (tid < 64) {
        float4 q4 = P[n0 + tid];
        qc[tid] = make_float4(-2.f * q4.x, -2.f * q4.y, -2.f * q4.z, 0.f);
        scnt[tid] = 0;
    }
    __syncthreads();

    // ---- load my 8 points (coalesced dwordx4, stay in VGPRs all kernel) ----
    const int base = w * SEG;
    float4 pt[PPL];
#pragma unroll
    for (int i = 0; i < PPL; ++i) pt[i] = P[base + i * 64 + lane];

    // ---- pass 1: per-(query, lane) minima over my 8 points ----
    float m[64];
#pragma unroll
    for (int q = 0; q < 64; ++q) {
        float4 c = qc[q];                  // ds_read_b128, static offset
        float mn = fmaf(c.x, pt[0].x, fmaf(c.y, pt[0].y, fmaf(c.z, pt[0].z, pt[0].w)));
#pragma unroll
        for (int i = 1; i < PPL; ++i) {
            float t = fmaf(c.x, pt[i].x, fmaf(c.y, pt[i].y, fmaf(c.z, pt[i].z, pt[i].w)));
            mn = fminf(mn, t);
        }
        m[q] = mn;
    }
#pragma unroll
    for (int q = 0; q < 64; ++q) atomicMin(&skey[q * 65 + lane], fkey(m[q]));
    __syncthreads();

    // ---- threshold: 16th smallest of the 64 class minima (thread = query) ----
    if (tid < 64) {
        unsigned t16[16];
#pragma unroll
        for (int i = 0; i < 16; ++i) t16[i] = 0xFFFFFFFFu;
        for (int c = 0; c < 64; ++c) {
            unsigned d = skey[tid * 65 + c];
            if (d < t16[15]) {
                t16[15] = d;
#pragma unroll
                for (int i = 15; i > 0; --i) {
                    unsigned a = t16[i - 1], cc = t16[i];
                    t16[i - 1] = umin_(a, cc);
                    t16[i]     = umax_(a, cc);
                }
            }
        }
        sT[tid] = funkey(t16[15]);
    }
    __syncthreads();

    // ---- pass 2: recompute from registers, append candidates ----
#pragma unroll
    for (int q = 0; q < 64; ++q) {
        float T = sT[q];
        if (m[q] <= T) {                   // whole-lane precheck (m is exact min)
            float4 c = qc[q];
#pragma unroll
            for (int i = 0; i < PPL; ++i) {
                float t = fmaf(c.x, pt[i].x, fmaf(c.y, pt[i].y, fmaf(c.z, pt[i].z, pt[i].w)));
                if (t <= T) {
                    int pos = atomicAdd(&scnt[q], 1);
                    if (pos < CAP) {
                        cand_t[pos * 64 + q] = t;
                        cand_i[pos * 64 + q] = base + i * 64 + lane;
                    }
                }
            }
        }
    }
    __syncthreads();

    // ---- exact selection among candidates (thread = query) ----
    if (tid < 64) {
        int cnt = scnt[tid];
        int* outp = idxout + ((bn0 + n0 + tid) << 4);
        float bd[16]; int bi[16];
#pragma unroll
        for (int i = 0; i < 16; ++i) { bd[i] = 3e38f; bi[i] = 0; }
        if (cnt <= CAP) {
            for (int pos = 0; pos < cnt; ++pos) {
                float d = cand_t[pos * 64 + tid];
                int   j = cand_i[pos * 64 + tid];
                if ((d < bd[15]) || (d == bd[15] && j < bi[15])) {
                    bd[15] = d; bi[15] = j;
#pragma unroll
                    for (int i = 15; i > 0; --i) {
                        bool sw = (bd[i] < bd[i - 1]) || (bd[i] == bd[i - 1] && bi[i] < bi[i - 1]);
                        float td = bd[i - 1]; int tj = bi[i - 1];
                        bd[i - 1] = sw ? bd[i] : td;  bi[i - 1] = sw ? bi[i] : tj;
                        bd[i]     = sw ? td : bd[i];  bi[i]     = sw ? tj : bi[i];
                    }
                }
            }
        } else {
            // overflow fallback (exact, never expected): bit-identical metric
            float4 q4 = P[n0 + tid];
            float cx = -2.f * q4.x, cy = -2.f * q4.y, cz = -2.f * q4.z;
            for (int j = 0; j < NP; ++j) {
                float4 p = P[j];
                float d = fmaf(cx, p.x, fmaf(cy, p.y, fmaf(cz, p.z, p.w)));
                if ((d < bd[15]) || (d == bd[15] && j < bi[15])) {
                    bd[15] = d; bi[15] = j;
#pragma unroll
                    for (int i = 15; i > 0; --i) {
                        bool sw = (bd[i] < bd[i - 1]) || (bd[i] == bd[i - 1] && bi[i] < bi[i - 1]);
                        float td = bd[i - 1]; int tj = bi[i - 1];
                        bd[i - 1] = sw ? bd[i] : td;  bi[i - 1] = sw ? bi[i] : tj;
                        bd[i]     = sw ? td : bd[i];  bi[i]     = sw ? tj : bi[i];
                    }
                }
            }
        }
#pragma unroll
        for (int i = 0; i < 16; ++i) outp[i] = bi[i];
    }
}

// ---------------------------------------------------------------------------
// Kernel 3: gather + conv0/1/2 + max over K. One thread per (n,k) column,
// 512-thread blocks (32 n x 16 k). feat gathered as bf16 (4x dwordx4 per
// neighbor). k-max via shfl_xor width 16.
// ---------------------------------------------------------------------------
__global__ __launch_bounds__(512, 4) void conv_kernel(
    const float4* __restrict__ pts4, const unsigned* __restrict__ featb,
    const int* __restrict__ idx,
    const float* __restrict__ W0, const float* __restrict__ W1, const float* __restrict__ W2,
    float* __restrict__ out)
{
    __shared__ float so[M2][33];
    const int tid = threadIdx.x;
    const int k   = tid & 15;
    const int nl  = tid >> 4;              // 0..31
    const int blk = blockIdx.x;            // 1024 blocks
    const int b   = blk >> 8;              // 256 blocks per batch
    const int n0  = (blk & 255) << 5;
    const int n   = n0 + nl;
    const int bn  = b * NP + n;
    const int j   = idx[(bn << 4) + k];
    const int bj  = b * NP + j;

    const float4 pc = pts4[bn];
    const float4 pj = pts4[bj];
    const float rx = pj.x - pc.x, ry = pj.y - pc.y, rz = pj.z - pc.z;

    const uint4* fj = (const uint4*)(featb + (size_t)bj * 16);

    float x0[M0];
#pragma unroll
    for (int g = 0; g < 4; ++g) {
        uint4 u = fj[g];
        const unsigned* uv = (const unsigned*)&u;
#pragma unroll
        for (int r = 0; r < 4; ++r) {
            int o = g * 8 + 2 * r;
            float fe  = __uint_as_float(uv[r] << 16);
            float fo_ = __uint_as_float(uv[r] & 0xffff0000u);
            x0[o]     = lrelu(fmaf(W0[o * 35], rx, fmaf(W0[o * 35 + 1], ry, fmaf(W0[o * 35 + 2], rz, fe))));
            x0[o + 1] = lrelu(fmaf(W0[(o + 1) * 35], rx, fmaf(W0[(o + 1) * 35 + 1], ry, fmaf(W0[(o + 1) * 35 + 2], rz, fo_))));
        }
    }

    float x1[M1];
#pragma unroll
    for (int o = 0; o < M1; ++o) {
        float acc = 0.f;
#pragma unroll
        for (int c = 0; c < M0; ++c) acc = fmaf(W1[o * 32 + c], x0[c], acc);
        x1[o] = lrelu(acc);
    }

#pragma unroll
    for (int o = 0; o < M2; ++o) {
        float acc = 0.f;
#pragma unroll
        for (int c = 0; c < M1; ++c) acc = fmaf(W2[o * 32 + c], x1[c], acc);
        float v = lrelu(acc);
        v = fmaxf(v, __shfl_xor(v, 1, 16));
        v = fmaxf(v, __shfl_xor(v, 2, 16));
        v = fmaxf(v, __shfl_xor(v, 4, 16));
        v = fmaxf(v, __shfl_xor(v, 8, 16));
        if (k == (o & 15)) so[o][nl] = v;
    }
    __syncthreads();
    {
        int o = tid >> 3;                 // 0..63
        int col = (tid & 7) << 2;         // 0..28
        float4 v = make_float4(so[o][col], so[o][col + 1], so[o][col + 2], so[o][col + 3]);
        *(float4*)(out + ((size_t)(b * M2 + o)) * NP + n0 + col) = v;
    }
}

// ---------------------------------------------------------------------------
extern "C" void kernel_launch(void* const* d_in, const int* in_sizes, int n_in,
                              void* d_out, int out_size, void* d_ws, size_t ws_size,
                              hipStream_t stream)
{
    const float* xyz    = (const float*)d_in[0];
    const float* points = (const float*)d_in[1];
    const float* W0     = (const float*)d_in[2];
    const float* W1     = (const float*)d_in[3];
    const float* W2     = (const float*)d_in[4];
    float* out = (float*)d_out;

    char* ws = (char*)d_ws;
    float4*   pts4  = (float4*)ws;                       // 512 KB
    unsigned* featb = (unsigned*)(ws + 0x100000);        // 2 MB
    int*      idx   = (int*)(ws + 0x300000);             // 2 MB

    prep_kernel<<<BB * NP / 64, 256,  0, stream>>>(xyz, points, W0, pts4, featb);
    knn_kernel <<<BB * NP / 64, 1024, 0, stream>>>(pts4, idx);
    conv_kernel<<<BB * NP / 32, 512,  0, stream>>>(pts4, featb, idx, W0, W1, W2, out);
}